// Round 2
// baseline (461.774 us; speedup 1.0000x reference)
//
#include <hip/hip_runtime.h>
#include <hip/hip_bf16.h>
#include <cstdint>
#include <cstddef>

#define EMBED 768
#define STREAMS 4
#define CHUNK 192          // EMBED / STREAMS
#define HEADS 12
#define HD 64
#define SEQ 1024
#define BATCH 8
#define TOKENS (BATCH * SEQ)   // 8192
#define MLPH 3072

typedef __bf16 bf16;
typedef __bf16 bf16x8 __attribute__((ext_vector_type(8)));
typedef float f32x4 __attribute__((ext_vector_type(4)));

// async global->LDS, 16B per lane; LDS dest must be linear in lane order
#define GLDS16(gp, lp)                                                        \
  __builtin_amdgcn_global_load_lds(                                           \
      (const __attribute__((address_space(1))) void*)(gp),                    \
      (__attribute__((address_space(3))) void*)(lp), 16, 0, 0)

// ---------------------------------------------------------------- hprep ----
// Sinkhorn (4x4, 20 iters) + softmax(4) for both mhc blocks. Trivial work.
// HS layout (floats): [s*24 + 0..15] H_res, [s*24+16..19] H_pre, [s*24+20..23] H_post
__global__ void hprep_kernel(const float* ar, const float* ap, const float* ao,
                             const float* mr, const float* mp, const float* mo,
                             float* HS) {
  if (threadIdx.x != 0) return;
  const float* L[2] = {ar, mr};
  const float* P[2] = {ap, mp};
  const float* O[2] = {ao, mo};
  for (int s = 0; s < 2; ++s) {
    float A[16];
    for (int i = 0; i < 16; ++i) A[i] = expf(L[s][i]);
    for (int it = 0; it < 20; ++it) {
      for (int r = 0; r < 4; ++r) {
        float rs = A[4*r] + A[4*r+1] + A[4*r+2] + A[4*r+3] + 1e-8f;
        for (int c = 0; c < 4; ++c) A[4*r+c] /= rs;
      }
      for (int c = 0; c < 4; ++c) {
        float cs = A[c] + A[4+c] + A[8+c] + A[12+c] + 1e-8f;
        for (int r = 0; r < 4; ++r) A[4*r+c] /= cs;
      }
    }
    float* dst = HS + s * 24;
    for (int i = 0; i < 16; ++i) dst[i] = A[i];
    {
      float m = fmaxf(fmaxf(P[s][0], P[s][1]), fmaxf(P[s][2], P[s][3]));
      float e[4], t = 0.f;
      for (int i = 0; i < 4; ++i) { e[i] = expf(P[s][i] - m); t += e[i]; }
      for (int i = 0; i < 4; ++i) dst[16 + i] = e[i] / t;
    }
    {
      float m = fmaxf(fmaxf(O[s][0], O[s][1]), fmaxf(O[s][2], O[s][3]));
      float e[4], t = 0.f;
      for (int i = 0; i < 4; ++i) { e[i] = expf(O[s][i] - m); t += e[i]; }
      for (int i = 0; i < 4; ++i) dst[20 + i] = e[i] / t;
    }
  }
}

// ------------------------------------------------------------------ cvt ----
__global__ void cvt_kernel(const float* __restrict__ in, bf16* __restrict__ out, int n) {
  int i = blockIdx.x * 256 + threadIdx.x;
  const int st = gridDim.x * 256;
  for (; i < n; i += st) out[i] = (bf16)in[i];
}

// ---------------------------------------------------------------- preln ----
// x_pre[c] = sum_n Hpre[n] * x[t, n*192+c]; LN of the 4x-tiled vector:
// stats over the 192 mixed values; out[d] = (s[d%192]-mu)*rs*g[d]+b[d] (bf16)
__global__ __launch_bounds__(256) void preln_kernel(
    const float* __restrict__ x, const float* __restrict__ H,
    const float* __restrict__ g, const float* __restrict__ b,
    bf16* __restrict__ out) {
  const int t = blockIdx.x;
  const float* xr = x + (size_t)t * EMBED;
  __shared__ float s[CHUNK];
  __shared__ float part[8];
  __shared__ float red[2];
  const int tid = threadIdx.x;
  float sv = 0.f;
  if (tid < CHUNK) {
    sv = H[0]*xr[tid] + H[1]*xr[CHUNK+tid] + H[2]*xr[2*CHUNK+tid] + H[3]*xr[3*CHUNK+tid];
    s[tid] = sv;
  }
  float sum = sv, sq = sv * sv;
  #pragma unroll
  for (int m = 32; m > 0; m >>= 1) {
    sum += __shfl_down(sum, m);
    sq  += __shfl_down(sq, m);
  }
  if ((tid & 63) == 0) { part[tid >> 6] = sum; part[4 + (tid >> 6)] = sq; }
  __syncthreads();
  if (tid == 0) {
    float S = part[0] + part[1] + part[2] + part[3];
    float Q = part[4] + part[5] + part[6] + part[7];
    float mu = S * (1.f / CHUNK);
    float var = Q * (1.f / CHUNK) - mu * mu;
    red[0] = mu;
    red[1] = rsqrtf(var + 1e-5f);
  }
  __syncthreads();
  const float mu = red[0], rs = red[1];
  bf16* orow = out + (size_t)t * EMBED;
  #pragma unroll
  for (int r = 0; r < 3; ++r) {
    const int d = tid + r * 256;
    const float v = (s[d % CHUNK] - mu) * rs * g[d] + b[d];
    orow[d] = (bf16)v;
  }
}

// ----------------------------------------------------------------- gemm ----
// C[m,n] = sum_k A[m,k]*B[n,k] + bias[n]; A (MxK), B (NxK) both bf16 row-major.
// 128x128 tile, BK=32, 4 waves each 64x64 (4x4 16x16 frags). m97 structure.
template <int GELU, int OUTF32>
__global__ __launch_bounds__(256) void gemm_bt(
    const bf16* __restrict__ A, const bf16* __restrict__ B,
    const float* __restrict__ bias, void* __restrict__ Cout,
    int M, int N, int K) {
  constexpr int BM = 128, BN = 128, BK = 32;
  __shared__ bf16 sA[BM * BK];
  __shared__ bf16 sB[BN * BK];
  const int tid  = threadIdx.x;
  const int lane = tid & 63;
  const int bm = blockIdx.y * BM;
  const int bn = blockIdx.x * BN;
  const int wave = tid >> 6;
  const int wr = (wave >> 1) * 64;
  const int wc = (wave & 1) * 64;
  f32x4 acc[4][4] = {};
  const int tr = tid >> 2;          // 0..63  staging row
  const int tc = (tid & 3) * 8;     // 0,8,16,24
  const bf16* Ag = A + (size_t)(bm + tr) * K + tc;
  const bf16* Bg = B + (size_t)(bn + tr) * K + tc;
  bf16* lA = sA + tr * BK + tc;
  bf16* lB = sB + tr * BK + tc;
  const int arow = wr + (lane & 15);
  const int brow = wc + (lane & 15);
  const int k0 = (lane >> 4) * 8;
  for (int bk = 0; bk < K; bk += BK) {
    __syncthreads();
    GLDS16(Ag + bk, lA);
    GLDS16(Ag + (size_t)64 * K + bk, lA + 64 * BK);
    GLDS16(Bg + bk, lB);
    GLDS16(Bg + (size_t)64 * K + bk, lB + 64 * BK);
    __syncthreads();
    bf16x8 af[4], bfr[4];
    #pragma unroll
    for (int i = 0; i < 4; ++i) af[i] = *(const bf16x8*)(sA + (arow + i * 16) * BK + k0);
    #pragma unroll
    for (int j = 0; j < 4; ++j) bfr[j] = *(const bf16x8*)(sB + (brow + j * 16) * BK + k0);
    #pragma unroll
    for (int i = 0; i < 4; ++i)
      #pragma unroll
      for (int j = 0; j < 4; ++j)
        acc[i][j] = __builtin_amdgcn_mfma_f32_16x16x32_bf16(af[i], bfr[j], acc[i][j], 0, 0, 0);
  }
  const int row0 = bm + wr + ((lane >> 4) * 4);
  const int col0 = bn + wc + (lane & 15);
  #pragma unroll
  for (int j = 0; j < 4; ++j) {
    const int col = col0 + j * 16;
    const float bv = bias[col];
    #pragma unroll
    for (int i = 0; i < 4; ++i) {
      #pragma unroll
      for (int r = 0; r < 4; ++r) {
        float v = acc[i][j][r] + bv;
        if (GELU) v = 0.5f * v * (1.f + erff(v * 0.70710678118654752f));
        const size_t off = (size_t)(row0 + i * 16 + r) * N + col;
        if (OUTF32) ((float*)Cout)[off] = v;
        else        ((bf16*)Cout)[off] = (bf16)v;
      }
    }
  }
}

// ----------------------------------------------------------------- attn ----
// Flash attention. grid (16 q-tiles, 96 b*h), 256 thr. Each wave: 16 q rows.
// qkv: (8192, 2304) bf16, cols = which*768 + h*64 + hd. out: (8192, 768) bf16.
__global__ __launch_bounds__(256) void attn_kernel(
    const bf16* __restrict__ qkv, bf16* __restrict__ out) {
  const int qt = blockIdx.x;
  const int bh = blockIdx.y;
  const int bb = bh / HEADS;
  const int h = bh - bb * HEADS;
  const int tid = threadIdx.x;
  const int lane = tid & 63;
  const int wave = tid >> 6;
  const size_t tokBase = (size_t)bb * SEQ;
  const int q0 = qt * 64;

  __shared__ bf16 sQ[64 * 64];
  __shared__ bf16 sK[64 * 64];
  __shared__ bf16 sVT[64 * 64];   // transposed: [hd][tok]
  __shared__ bf16 sP[4][16 * 64]; // per wave

  const int srow = tid >> 3;        // 0..31
  const int scol = (tid & 7) * 8;   // 0..56
  {
    const bf16* Qg = qkv + (tokBase + q0 + srow) * 2304 + h * 64 + scol;
    GLDS16(Qg, sQ + srow * 64 + scol);
    GLDS16(Qg + 32 * 2304, sQ + (32 + srow) * 64 + scol);
  }
  __syncthreads();
  const int l15 = lane & 15, hi = lane >> 4;
  bf16x8 qf[2];
  #pragma unroll
  for (int ks = 0; ks < 2; ++ks)
    qf[ks] = *(const bf16x8*)(sQ + (wave * 16 + l15) * 64 + hi * 8 + ks * 32);

  f32x4 o[4] = {};
  float mrun[4], lrun[4];
  #pragma unroll
  for (int r = 0; r < 4; ++r) { mrun[r] = -1e30f; lrun[r] = 0.f; }

  for (int kb = 0; kb < SEQ; kb += 64) {
    __syncthreads();   // previous tile's LDS reads done
    const bf16* Kg = qkv + (tokBase + kb + srow) * 2304 + 768 + h * 64 + scol;
    GLDS16(Kg, sK + srow * 64 + scol);
    GLDS16(Kg + 32 * 2304, sK + (32 + srow) * 64 + scol);
    const bf16* Vg = qkv + (tokBase + kb + srow) * 2304 + 1536 + h * 64 + scol;
    bf16x8 v0 = *(const bf16x8*)(Vg);
    bf16x8 v1 = *(const bf16x8*)(Vg + 32 * 2304);
    #pragma unroll
    for (int e = 0; e < 8; ++e) {
      sVT[(scol + e) * 64 + srow]      = v0[e];
      sVT[(scol + e) * 64 + 32 + srow] = v1[e];
    }
    __syncthreads();
    // S = Q K^T  (16 x 64 per wave)
    f32x4 s[4];
    #pragma unroll
    for (int nj = 0; nj < 4; ++nj) {
      s[nj] = (f32x4){0.f, 0.f, 0.f, 0.f};
      #pragma unroll
      for (int ks = 0; ks < 2; ++ks) {
        bf16x8 kf = *(const bf16x8*)(sK + (nj * 16 + l15) * 64 + hi * 8 + ks * 32);
        s[nj] = __builtin_amdgcn_mfma_f32_16x16x32_bf16(qf[ks], kf, s[nj], 0, 0, 0);
      }
    }
    // online softmax; scale = 1/8
    float p[4][4], tmax[4];
    #pragma unroll
    for (int r = 0; r < 4; ++r) {
      float m = fmaxf(fmaxf(s[0][r], s[1][r]), fmaxf(s[2][r], s[3][r]));
      tmax[r] = m * 0.125f;
    }
    #pragma unroll
    for (int r = 0; r < 4; ++r) {
      #pragma unroll
      for (int mm = 1; mm < 16; mm <<= 1) tmax[r] = fmaxf(tmax[r], __shfl_xor(tmax[r], mm));
    }
    float alpha[4], psum[4];
    #pragma unroll
    for (int r = 0; r < 4; ++r) {
      const float mnew = fmaxf(mrun[r], tmax[r]);
      alpha[r] = __expf(mrun[r] - mnew);
      mrun[r] = mnew;
      float ps = 0.f;
      #pragma unroll
      for (int nj = 0; nj < 4; ++nj) {
        const float pv = __expf(s[nj][r] * 0.125f - mnew);
        p[nj][r] = pv;
        ps += pv;
      }
      psum[r] = ps;
    }
    #pragma unroll
    for (int r = 0; r < 4; ++r) {
      #pragma unroll
      for (int mm = 1; mm < 16; mm <<= 1) psum[r] += __shfl_xor(psum[r], mm);
      lrun[r] = lrun[r] * alpha[r] + psum[r];
    }
    #pragma unroll
    for (int nj = 0; nj < 4; ++nj)
      #pragma unroll
      for (int r = 0; r < 4; ++r)
        o[nj][r] *= alpha[r];
    // P -> LDS (per-wave; intra-wave DS ordering guarantees visibility)
    bf16* Pw = sP[wave];
    #pragma unroll
    for (int nj = 0; nj < 4; ++nj)
      #pragma unroll
      for (int r = 0; r < 4; ++r)
        Pw[(hi * 4 + r) * 64 + nj * 16 + l15] = (bf16)p[nj][r];
    // O += P V
    #pragma unroll
    for (int ks = 0; ks < 2; ++ks) {
      bf16x8 pa = *(const bf16x8*)(Pw + l15 * 64 + hi * 8 + ks * 32);
      #pragma unroll
      for (int nj = 0; nj < 4; ++nj) {
        bf16x8 vb = *(const bf16x8*)(sVT + (nj * 16 + l15) * 64 + hi * 8 + ks * 32);
        o[nj] = __builtin_amdgcn_mfma_f32_16x16x32_bf16(pa, vb, o[nj], 0, 0, 0);
      }
    }
  }
  #pragma unroll
  for (int r = 0; r < 4; ++r) {
    const float inv = 1.f / lrun[r];
    const size_t row = tokBase + q0 + wave * 16 + hi * 4 + r;
    bf16* orow = out + row * EMBED + h * 64;
    #pragma unroll
    for (int nj = 0; nj < 4; ++nj)
      orow[nj * 16 + l15] = (bf16)(o[nj][r] * inv);
  }
}

// -------------------------------------------------------------- combine ----
// out[t, n*192+c] = sum_m Hres[n][m]*xs[t, m*192+c] + Hpost[n]*t_mean[t,c]
// d_out is FLOAT32 (reference output dtype) — always write f32 here.
__global__ void combine_kernel(const float* __restrict__ xs, const float* __restrict__ t,
                               const float* __restrict__ Hres, const float* __restrict__ Hpost,
                               float* __restrict__ outp) {
  const int idx = blockIdx.x * 256 + threadIdx.x;
  if (idx >= TOKENS * CHUNK) return;
  const int tok = idx / CHUNK;
  const int c = idx - tok * CHUNK;
  const float* xr = xs + (size_t)tok * EMBED + c;
  const float* tr = t + (size_t)tok * EMBED + c;
  const float x0 = xr[0], x1 = xr[CHUNK], x2 = xr[2 * CHUNK], x3 = xr[3 * CHUNK];
  const float tm = 0.25f * (tr[0] + tr[CHUNK] + tr[2 * CHUNK] + tr[3 * CHUNK]);
  #pragma unroll
  for (int n = 0; n < 4; ++n) {
    const float v = Hres[4*n+0]*x0 + Hres[4*n+1]*x1 + Hres[4*n+2]*x2 + Hres[4*n+3]*x3
                  + Hpost[n] * tm;
    outp[(size_t)tok * EMBED + n * CHUNK + c] = v;
  }
}

// ---------------------------------------------------------------- launch ---
extern "C" void kernel_launch(void* const* d_in, const int* in_sizes, int n_in,
                              void* d_out, int out_size, void* d_ws, size_t ws_size,
                              hipStream_t stream) {
  const float* x       = (const float*)d_in[0];
  const float* ln1_g   = (const float*)d_in[1];
  const float* ln1_b   = (const float*)d_in[2];
  const float* ln2_g   = (const float*)d_in[3];
  const float* ln2_b   = (const float*)d_in[4];
  const float* qkv_w   = (const float*)d_in[5];
  const float* qkv_b   = (const float*)d_in[6];
  const float* proj_w  = (const float*)d_in[7];
  const float* proj_b  = (const float*)d_in[8];
  const float* fc1_w   = (const float*)d_in[9];
  const float* fc1_b   = (const float*)d_in[10];
  const float* fc2_w   = (const float*)d_in[11];
  const float* fc2_b   = (const float*)d_in[12];
  const float* a_hres  = (const float*)d_in[13];
  const float* a_hpre  = (const float*)d_in[14];
  const float* a_hpost = (const float*)d_in[15];
  const float* m_hres  = (const float*)d_in[16];
  const float* m_hpre  = (const float*)d_in[17];
  const float* m_hpost = (const float*)d_in[18];

  char* ws = (char*)d_ws;
  // static overlay layout (127,403,008 B total)
  float* HS = (float*)(ws);                                  // 48 floats
  bf16* Wq  = (bf16*)(ws + 1024);                            // 2304x768
  bf16* Wp  = (bf16*)(ws + 1024 + 3538944);                  // 768x768
  bf16* W1  = (bf16*)(ws + 1024 + 3538944 + 1179648);        // 3072x768
  bf16* W2  = (bf16*)(ws + 1024 + 3538944 + 1179648 + 4718592); // 768x3072
  bf16* LN  = (bf16*)(ws + 14156800);                        // 8192x768 bf16
  float* T  = (float*)(ws + 26739712);                       // 8192x768 f32
  float* X2 = (float*)(ws + 51905536);                       // 8192x768 f32
  bf16* QKV = (bf16*)(ws + 77071360);                        // 8192x2304 bf16
  bf16* AO  = (bf16*)(ws + 114820096);                       // 8192x768 bf16
  bf16* Hm  = (bf16*)(ws + 77071360);                        // 8192x3072 (overlays QKV+AO)

  hprep_kernel<<<1, 64, 0, stream>>>(a_hres, a_hpre, a_hpost, m_hres, m_hpre, m_hpost, HS);
  cvt_kernel<<<1024, 256, 0, stream>>>(qkv_w, Wq, 2304 * 768);
  cvt_kernel<<<1024, 256, 0, stream>>>(proj_w, Wp, 768 * 768);
  cvt_kernel<<<1024, 256, 0, stream>>>(fc1_w, W1, 3072 * 768);
  cvt_kernel<<<1024, 256, 0, stream>>>(fc2_w, W2, 768 * 3072);

  // ---- block 1: attention mhc ----
  preln_kernel<<<TOKENS, 256, 0, stream>>>(x, HS + 16, ln1_g, ln1_b, LN);
  gemm_bt<0, 0><<<dim3(2304 / 128, TOKENS / 128), 256, 0, stream>>>(LN, Wq, qkv_b, QKV, TOKENS, 2304, 768);
  attn_kernel<<<dim3(16, 96), 256, 0, stream>>>(QKV, AO);
  gemm_bt<0, 1><<<dim3(768 / 128, TOKENS / 128), 256, 0, stream>>>(AO, Wp, proj_b, T, TOKENS, 768, 768);
  combine_kernel<<<(TOKENS * CHUNK + 255) / 256, 256, 0, stream>>>(x, T, HS + 0, HS + 20, X2);

  // ---- block 2: MLP mhc ----
  preln_kernel<<<TOKENS, 256, 0, stream>>>(X2, HS + 24 + 16, ln2_g, ln2_b, LN);
  gemm_bt<1, 0><<<dim3(3072 / 128, TOKENS / 128), 256, 0, stream>>>(LN, W1, fc1_b, Hm, TOKENS, 3072, 768);
  gemm_bt<0, 1><<<dim3(768 / 128, TOKENS / 128), 256, 0, stream>>>(Hm, W2, fc2_b, T, TOKENS, 768, 3072);
  combine_kernel<<<(TOKENS * CHUNK + 255) / 256, 256, 0, stream>>>(X2, T, HS + 24, HS + 24 + 20, (float*)d_out);
}

// Round 3
// 397.135 us; speedup vs baseline: 1.1628x; 1.1628x over previous
//
#include <hip/hip_runtime.h>
#include <hip/hip_bf16.h>
#include <cstdint>
#include <cstddef>

#define EMBED 768
#define STREAMS 4
#define CHUNK 192          // EMBED / STREAMS
#define HEADS 12
#define HD 64
#define SEQ 1024
#define BATCH 8
#define TOKENS (BATCH * SEQ)   // 8192
#define MLPH 3072

typedef __bf16 bf16;
typedef __bf16 bf16x8 __attribute__((ext_vector_type(8)));
typedef float f32x4 __attribute__((ext_vector_type(4)));

// async global->LDS, 16B per lane; LDS dest must be linear in lane order
#define GLDS16(gp, lp)                                                        \
  __builtin_amdgcn_global_load_lds(                                           \
      (const __attribute__((address_space(1))) void*)(gp),                    \
      (__attribute__((address_space(3))) void*)(lp), 16, 0, 0)

// ---------------------------------------------------------------- hprep ----
__global__ void hprep_kernel(const float* ar, const float* ap, const float* ao,
                             const float* mr, const float* mp, const float* mo,
                             float* HS) {
  if (threadIdx.x != 0) return;
  const float* L[2] = {ar, mr};
  const float* P[2] = {ap, mp};
  const float* O[2] = {ao, mo};
  for (int s = 0; s < 2; ++s) {
    float A[16];
    for (int i = 0; i < 16; ++i) A[i] = expf(L[s][i]);
    for (int it = 0; it < 20; ++it) {
      for (int r = 0; r < 4; ++r) {
        float rs = A[4*r] + A[4*r+1] + A[4*r+2] + A[4*r+3] + 1e-8f;
        for (int c = 0; c < 4; ++c) A[4*r+c] /= rs;
      }
      for (int c = 0; c < 4; ++c) {
        float cs = A[c] + A[4+c] + A[8+c] + A[12+c] + 1e-8f;
        for (int r = 0; r < 4; ++r) A[4*r+c] /= cs;
      }
    }
    float* dst = HS + s * 24;
    for (int i = 0; i < 16; ++i) dst[i] = A[i];
    {
      float m = fmaxf(fmaxf(P[s][0], P[s][1]), fmaxf(P[s][2], P[s][3]));
      float e[4], t = 0.f;
      for (int i = 0; i < 4; ++i) { e[i] = expf(P[s][i] - m); t += e[i]; }
      for (int i = 0; i < 4; ++i) dst[16 + i] = e[i] / t;
    }
    {
      float m = fmaxf(fmaxf(O[s][0], O[s][1]), fmaxf(O[s][2], O[s][3]));
      float e[4], t = 0.f;
      for (int i = 0; i < 4; ++i) { e[i] = expf(O[s][i] - m); t += e[i]; }
      for (int i = 0; i < 4; ++i) dst[20 + i] = e[i] / t;
    }
  }
}

// ------------------------------------------------------------------ cvt ----
__global__ void cvt_kernel(const float* __restrict__ in, bf16* __restrict__ out, int n) {
  int i = blockIdx.x * 256 + threadIdx.x;
  const int st = gridDim.x * 256;
  for (; i < n; i += st) out[i] = (bf16)in[i];
}

// ---------------------------------------------------------------- preln ----
__global__ __launch_bounds__(256) void preln_kernel(
    const float* __restrict__ x, const float* __restrict__ H,
    const float* __restrict__ g, const float* __restrict__ b,
    bf16* __restrict__ out) {
  const int t = blockIdx.x;
  const float* xr = x + (size_t)t * EMBED;
  __shared__ float s[CHUNK];
  __shared__ float part[8];
  __shared__ float red[2];
  const int tid = threadIdx.x;
  float sv = 0.f;
  if (tid < CHUNK) {
    sv = H[0]*xr[tid] + H[1]*xr[CHUNK+tid] + H[2]*xr[2*CHUNK+tid] + H[3]*xr[3*CHUNK+tid];
    s[tid] = sv;
  }
  float sum = sv, sq = sv * sv;
  #pragma unroll
  for (int m = 32; m > 0; m >>= 1) {
    sum += __shfl_down(sum, m);
    sq  += __shfl_down(sq, m);
  }
  if ((tid & 63) == 0) { part[tid >> 6] = sum; part[4 + (tid >> 6)] = sq; }
  __syncthreads();
  if (tid == 0) {
    float S = part[0] + part[1] + part[2] + part[3];
    float Q = part[4] + part[5] + part[6] + part[7];
    float mu = S * (1.f / CHUNK);
    float var = Q * (1.f / CHUNK) - mu * mu;
    red[0] = mu;
    red[1] = rsqrtf(var + 1e-5f);
  }
  __syncthreads();
  const float mu = red[0], rs = red[1];
  bf16* orow = out + (size_t)t * EMBED;
  #pragma unroll
  for (int r = 0; r < 3; ++r) {
    const int d = tid + r * 256;
    const float v = (s[d % CHUNK] - mu) * rs * g[d] + b[d];
    orow[d] = (bf16)v;
  }
}

// ----------------------------------------------------------------- gemm ----
// C[m,n] = sum_k A[m,k]*B[n,k] + bias[n]; m97 structure + T1 XCD swizzle.
// NOTE: launch grids must have gridDim.x*gridDim.y % 8 == 0 (all ours do).
template <int GELU, int OUTF32>
__global__ __launch_bounds__(256) void gemm_bt(
    const bf16* __restrict__ A, const bf16* __restrict__ B,
    const float* __restrict__ bias, void* __restrict__ Cout,
    int M, int N, int K) {
  constexpr int BM = 128, BN = 128, BK = 32;
  __shared__ bf16 sA[BM * BK];
  __shared__ bf16 sB[BN * BK];
  const int tid  = threadIdx.x;
  const int lane = tid & 63;
  // T1: XCD-aware bijective block swizzle (nwg % 8 == 0)
  const int nwg = gridDim.x * gridDim.y;
  int L = blockIdx.y * gridDim.x + blockIdx.x;
  L = (L & 7) * (nwg >> 3) + (L >> 3);
  const int bm = (L / gridDim.x) * BM;
  const int bn = (L % gridDim.x) * BN;
  const int wave = tid >> 6;
  const int wr = (wave >> 1) * 64;
  const int wc = (wave & 1) * 64;
  f32x4 acc[4][4] = {};
  const int tr = tid >> 2;          // 0..63  staging row
  const int tc = (tid & 3) * 8;     // 0,8,16,24
  const bf16* Ag = A + (size_t)(bm + tr) * K + tc;
  const bf16* Bg = B + (size_t)(bn + tr) * K + tc;
  bf16* lA = sA + tr * BK + tc;
  bf16* lB = sB + tr * BK + tc;
  const int arow = wr + (lane & 15);
  const int brow = wc + (lane & 15);
  const int k0 = (lane >> 4) * 8;
  for (int bk = 0; bk < K; bk += BK) {
    __syncthreads();
    GLDS16(Ag + bk, lA);
    GLDS16(Ag + (size_t)64 * K + bk, lA + 64 * BK);
    GLDS16(Bg + bk, lB);
    GLDS16(Bg + (size_t)64 * K + bk, lB + 64 * BK);
    __syncthreads();
    bf16x8 af[4], bfr[4];
    #pragma unroll
    for (int i = 0; i < 4; ++i) af[i] = *(const bf16x8*)(sA + (arow + i * 16) * BK + k0);
    #pragma unroll
    for (int j = 0; j < 4; ++j) bfr[j] = *(const bf16x8*)(sB + (brow + j * 16) * BK + k0);
    #pragma unroll
    for (int i = 0; i < 4; ++i)
      #pragma unroll
      for (int j = 0; j < 4; ++j)
        acc[i][j] = __builtin_amdgcn_mfma_f32_16x16x32_bf16(af[i], bfr[j], acc[i][j], 0, 0, 0);
  }
  const int row0 = bm + wr + ((lane >> 4) * 4);
  const int col0 = bn + wc + (lane & 15);
  #pragma unroll
  for (int j = 0; j < 4; ++j) {
    const int col = col0 + j * 16;
    const float bv = bias[col];
    #pragma unroll
    for (int i = 0; i < 4; ++i) {
      #pragma unroll
      for (int r = 0; r < 4; ++r) {
        float v = acc[i][j][r] + bv;
        if (GELU) v = 0.5f * v * (1.f + erff(v * 0.70710678118654752f));
        const size_t off = (size_t)(row0 + i * 16 + r) * N + col;
        if (OUTF32) ((float*)Cout)[off] = v;
        else        ((bf16*)Cout)[off] = (bf16)v;
      }
    }
  }
}

// ------------------------------------------------------------------- vt ----
// VT[bh][hd][tok] = qkv[bb*1024+tok][1536 + h*64 + hd]; swizzled LDS stage.
__global__ __launch_bounds__(256) void vt_kernel(const bf16* __restrict__ qkv,
                                                 bf16* __restrict__ VT) {
  const int tt = blockIdx.x;   // 16 tok tiles of 64
  const int bh = blockIdx.y;   // 96
  const int bb = bh / HEADS;
  const int h = bh - bb * HEADS;
  __shared__ bf16 sT[64 * 64];
  const int t = threadIdx.x;
  const int srow = t >> 3;            // 0..31 (tok within half-tile)
  const int g = t & 7;                // 16B granule
  const int gs = ((g ^ (srow & 7)) * 8);
  const bf16* Vg = qkv + ((size_t)(bb * SEQ + tt * 64 + srow)) * 2304 + 1536 + h * 64;
  GLDS16(Vg + gs, sT + srow * 64 + g * 8);
  GLDS16(Vg + (size_t)32 * 2304 + gs, sT + (32 + srow) * 64 + g * 8);
  __syncthreads();
  const int hd = t >> 2;
  const int tg = (t & 3) * 16;
  bf16 tmp[16];
  #pragma unroll
  for (int j = 0; j < 16; ++j) {
    const int tok = tg + j;
    tmp[j] = sT[tok * 64 + (hd ^ ((tok & 7) << 3))];
  }
  bf16* op = VT + (size_t)bh * (HD * SEQ) + (size_t)hd * SEQ + tt * 64 + tg;
  *(bf16x8*)(op) = *(const bf16x8*)(tmp);
  *(bf16x8*)(op + 8) = *(const bf16x8*)(tmp + 8);
}

// ----------------------------------------------------------------- attn ----
// Flash attention, all LDS tiles XOR-swizzled (elem ^ ((row&7)<<3)).
// Staging: linear LDS dest + pre-swizzled global source (rule #21).
__global__ __launch_bounds__(256) void attn_kernel(
    const bf16* __restrict__ qkv, const bf16* __restrict__ VT,
    bf16* __restrict__ out) {
  const int qt = blockIdx.x;
  const int bh = blockIdx.y;
  const int bb = bh / HEADS;
  const int h = bh - bb * HEADS;
  const int tid = threadIdx.x;
  const int lane = tid & 63;
  const int wave = tid >> 6;
  const size_t tokBase = (size_t)bb * SEQ;
  const int q0 = qt * 64;

  __shared__ bf16 sQ[64 * 64];
  __shared__ bf16 sK[64 * 64];
  __shared__ bf16 sV[64 * 64];    // V^T tile: rows = hd, cols = tok
  __shared__ bf16 sP[4][16 * 64]; // per wave, swizzled

  const int srow = tid >> 3;          // 0..31
  const int g = tid & 7;
  const int gs = ((g ^ (srow & 7)) * 8);   // pre-swizzled source granule
  {
    const bf16* Qg = qkv + (tokBase + q0 + srow) * 2304 + h * 64;
    GLDS16(Qg + gs, sQ + srow * 64 + g * 8);
    GLDS16(Qg + (size_t)32 * 2304 + gs, sQ + (32 + srow) * 64 + g * 8);
  }
  __syncthreads();
  const int l15 = lane & 15, hi = lane >> 4;
  const int ksw = (l15 & 7) << 3;     // read-side swizzle for rows ≡ l15 (mod 8)
  bf16x8 qf[2];
  {
    const int qrow = wave * 16 + l15;
    const int qsw = (qrow & 7) << 3;
    #pragma unroll
    for (int ks = 0; ks < 2; ++ks)
      qf[ks] = *(const bf16x8*)(sQ + qrow * 64 + ((hi * 8 + ks * 32) ^ qsw));
  }

  f32x4 o[4] = {};
  float mrun[4], lrun[4];
  #pragma unroll
  for (int r = 0; r < 4; ++r) { mrun[r] = -1e30f; lrun[r] = 0.f; }

  for (int kb = 0; kb < SEQ; kb += 64) {
    __syncthreads();   // previous tile's LDS reads done
    {
      const bf16* Kg = qkv + (tokBase + kb + srow) * 2304 + 768 + h * 64;
      GLDS16(Kg + gs, sK + srow * 64 + g * 8);
      GLDS16(Kg + (size_t)32 * 2304 + gs, sK + (32 + srow) * 64 + g * 8);
      const bf16* Vg = VT + (size_t)bh * (HD * SEQ) + (size_t)srow * SEQ + kb;
      GLDS16(Vg + gs, sV + srow * 64 + g * 8);
      GLDS16(Vg + (size_t)32 * SEQ + gs, sV + (32 + srow) * 64 + g * 8);
    }
    __syncthreads();
    // S = Q K^T  (16 x 64 per wave)
    f32x4 s[4];
    #pragma unroll
    for (int nj = 0; nj < 4; ++nj) {
      s[nj] = (f32x4){0.f, 0.f, 0.f, 0.f};
      #pragma unroll
      for (int ks = 0; ks < 2; ++ks) {
        bf16x8 kf = *(const bf16x8*)(sK + (nj * 16 + l15) * 64 + ((hi * 8 + ks * 32) ^ ksw));
        s[nj] = __builtin_amdgcn_mfma_f32_16x16x32_bf16(qf[ks], kf, s[nj], 0, 0, 0);
      }
    }
    // online softmax; scale = 1/8
    float p[4][4], tmax[4];
    #pragma unroll
    for (int r = 0; r < 4; ++r) {
      float m = fmaxf(fmaxf(s[0][r], s[1][r]), fmaxf(s[2][r], s[3][r]));
      tmax[r] = m * 0.125f;
    }
    #pragma unroll
    for (int r = 0; r < 4; ++r) {
      #pragma unroll
      for (int mm = 1; mm < 16; mm <<= 1) tmax[r] = fmaxf(tmax[r], __shfl_xor(tmax[r], mm));
    }
    float alpha[4], psum[4];
    #pragma unroll
    for (int r = 0; r < 4; ++r) {
      const float mnew = fmaxf(mrun[r], tmax[r]);
      alpha[r] = __expf(mrun[r] - mnew);
      mrun[r] = mnew;
      float ps = 0.f;
      #pragma unroll
      for (int nj = 0; nj < 4; ++nj) {
        const float pv = __expf(s[nj][r] * 0.125f - mnew);
        p[nj][r] = pv;
        ps += pv;
      }
      psum[r] = ps;
    }
    #pragma unroll
    for (int r = 0; r < 4; ++r) {
      #pragma unroll
      for (int mm = 1; mm < 16; mm <<= 1) psum[r] += __shfl_xor(psum[r], mm);
      lrun[r] = lrun[r] * alpha[r] + psum[r];
    }
    #pragma unroll
    for (int nj = 0; nj < 4; ++nj)
      #pragma unroll
      for (int r = 0; r < 4; ++r)
        o[nj][r] *= alpha[r];
    // P -> LDS (per-wave, swizzled; intra-wave DS ordering gives visibility)
    bf16* Pw = sP[wave];
    #pragma unroll
    for (int r = 0; r < 4; ++r) {
      const int prow = hi * 4 + r;
      const int psw = (prow & 7) << 3;
      #pragma unroll
      for (int nj = 0; nj < 4; ++nj)
        Pw[prow * 64 + ((nj * 16 + l15) ^ psw)] = (bf16)p[nj][r];
    }
    // O += P V
    #pragma unroll
    for (int ks = 0; ks < 2; ++ks) {
      bf16x8 pa = *(const bf16x8*)(Pw + l15 * 64 + ((hi * 8 + ks * 32) ^ ksw));
      #pragma unroll
      for (int nj = 0; nj < 4; ++nj) {
        bf16x8 vb = *(const bf16x8*)(sV + (nj * 16 + l15) * 64 + ((hi * 8 + ks * 32) ^ ksw));
        o[nj] = __builtin_amdgcn_mfma_f32_16x16x32_bf16(pa, vb, o[nj], 0, 0, 0);
      }
    }
  }
  #pragma unroll
  for (int r = 0; r < 4; ++r) {
    const float inv = 1.f / lrun[r];
    const size_t row = tokBase + q0 + wave * 16 + hi * 4 + r;
    bf16* orow = out + row * EMBED + h * 64;
    #pragma unroll
    for (int nj = 0; nj < 4; ++nj)
      orow[nj * 16 + l15] = (bf16)(o[nj][r] * inv);
  }
}

// -------------------------------------------------------------- combine ----
__global__ void combine_kernel(const float* __restrict__ xs, const float* __restrict__ t,
                               const float* __restrict__ Hres, const float* __restrict__ Hpost,
                               float* __restrict__ outp) {
  const int idx = blockIdx.x * 256 + threadIdx.x;
  if (idx >= TOKENS * CHUNK) return;
  const int tok = idx / CHUNK;
  const int c = idx - tok * CHUNK;
  const float* xr = xs + (size_t)tok * EMBED + c;
  const float* tr = t + (size_t)tok * EMBED + c;
  const float x0 = xr[0], x1 = xr[CHUNK], x2 = xr[2 * CHUNK], x3 = xr[3 * CHUNK];
  const float tm = 0.25f * (tr[0] + tr[CHUNK] + tr[2 * CHUNK] + tr[3 * CHUNK]);
  #pragma unroll
  for (int n = 0; n < 4; ++n) {
    const float v = Hres[4*n+0]*x0 + Hres[4*n+1]*x1 + Hres[4*n+2]*x2 + Hres[4*n+3]*x3
                  + Hpost[n] * tm;
    outp[(size_t)tok * EMBED + n * CHUNK + c] = v;
  }
}

// ---------------------------------------------------------------- launch ---
extern "C" void kernel_launch(void* const* d_in, const int* in_sizes, int n_in,
                              void* d_out, int out_size, void* d_ws, size_t ws_size,
                              hipStream_t stream) {
  const float* x       = (const float*)d_in[0];
  const float* ln1_g   = (const float*)d_in[1];
  const float* ln1_b   = (const float*)d_in[2];
  const float* ln2_g   = (const float*)d_in[3];
  const float* ln2_b   = (const float*)d_in[4];
  const float* qkv_w   = (const float*)d_in[5];
  const float* qkv_b   = (const float*)d_in[6];
  const float* proj_w  = (const float*)d_in[7];
  const float* proj_b  = (const float*)d_in[8];
  const float* fc1_w   = (const float*)d_in[9];
  const float* fc1_b   = (const float*)d_in[10];
  const float* fc2_w   = (const float*)d_in[11];
  const float* fc2_b   = (const float*)d_in[12];
  const float* a_hres  = (const float*)d_in[13];
  const float* a_hpre  = (const float*)d_in[14];
  const float* a_hpost = (const float*)d_in[15];
  const float* m_hres  = (const float*)d_in[16];
  const float* m_hpre  = (const float*)d_in[17];
  const float* m_hpost = (const float*)d_in[18];

  char* ws = (char*)d_ws;
  // static overlay layout (127,403,008 B total)
  float* HS = (float*)(ws);                                  // 48 floats
  bf16* Wq  = (bf16*)(ws + 1024);                            // 2304x768
  bf16* Wp  = (bf16*)(ws + 1024 + 3538944);                  // 768x768
  bf16* W1  = (bf16*)(ws + 1024 + 3538944 + 1179648);        // 3072x768
  bf16* W2  = (bf16*)(ws + 1024 + 3538944 + 1179648 + 4718592); // 768x3072
  bf16* LN  = (bf16*)(ws + 14156800);                        // 8192x768 bf16
  float* T  = (float*)(ws + 26739712);                       // 8192x768 f32
  float* X2 = (float*)(ws + 51905536);                       // 8192x768 f32
  bf16* QKV = (bf16*)(ws + 77071360);                        // 8192x2304 bf16
  bf16* AO  = (bf16*)(ws + 114820096);                       // 8192x768 bf16
  bf16* Hm  = (bf16*)(ws + 77071360);                        // 8192x3072 (overlays QKV+AO)
  bf16* VT  = LN;   // 96x64x1024 bf16 = 12,582,912 B — overlays LN (dead after qkv GEMM)

  hprep_kernel<<<1, 64, 0, stream>>>(a_hres, a_hpre, a_hpost, m_hres, m_hpre, m_hpost, HS);
  cvt_kernel<<<1024, 256, 0, stream>>>(qkv_w, Wq, 2304 * 768);
  cvt_kernel<<<1024, 256, 0, stream>>>(proj_w, Wp, 768 * 768);
  cvt_kernel<<<1024, 256, 0, stream>>>(fc1_w, W1, 3072 * 768);
  cvt_kernel<<<1024, 256, 0, stream>>>(fc2_w, W2, 768 * 3072);

  // ---- block 1: attention mhc ----
  preln_kernel<<<TOKENS, 256, 0, stream>>>(x, HS + 16, ln1_g, ln1_b, LN);
  gemm_bt<0, 0><<<dim3(2304 / 128, TOKENS / 128), 256, 0, stream>>>(LN, Wq, qkv_b, QKV, TOKENS, 2304, 768);
  vt_kernel<<<dim3(16, 96), 256, 0, stream>>>(QKV, VT);
  attn_kernel<<<dim3(16, 96), 256, 0, stream>>>(QKV, VT, AO);
  gemm_bt<0, 1><<<dim3(768 / 128, TOKENS / 128), 256, 0, stream>>>(AO, Wp, proj_b, T, TOKENS, 768, 768);
  combine_kernel<<<(TOKENS * CHUNK + 255) / 256, 256, 0, stream>>>(x, T, HS + 0, HS + 20, X2);

  // ---- block 2: MLP mhc ----
  preln_kernel<<<TOKENS, 256, 0, stream>>>(X2, HS + 24 + 16, ln2_g, ln2_b, LN);
  gemm_bt<1, 0><<<dim3(3072 / 128, TOKENS / 128), 256, 0, stream>>>(LN, W1, fc1_b, Hm, TOKENS, 3072, 768);
  gemm_bt<0, 1><<<dim3(768 / 128, TOKENS / 128), 256, 0, stream>>>(Hm, W2, fc2_b, T, TOKENS, 768, 3072);
  combine_kernel<<<(TOKENS * CHUNK + 255) / 256, 256, 0, stream>>>(X2, T, HS + 24, HS + 24 + 20, (float*)d_out);
}

// Round 4
// 368.997 us; speedup vs baseline: 1.2514x; 1.0763x over previous
//
#include <hip/hip_runtime.h>
#include <hip/hip_bf16.h>
#include <cstdint>
#include <cstddef>

#define EMBED 768
#define STREAMS 4
#define CHUNK 192          // EMBED / STREAMS
#define HEADS 12
#define HD 64
#define SEQ 1024
#define BATCH 8
#define TOKENS (BATCH * SEQ)   // 8192
#define MLPH 3072

typedef __bf16 bf16;
typedef __bf16 bf16x4 __attribute__((ext_vector_type(4)));
typedef __bf16 bf16x8 __attribute__((ext_vector_type(8)));
typedef float f32x4 __attribute__((ext_vector_type(4)));

// async global->LDS, 16B per lane; LDS dest must be linear in lane order
#define GLDS16(gp, lp)                                                        \
  __builtin_amdgcn_global_load_lds(                                           \
      (const __attribute__((address_space(1))) void*)(gp),                    \
      (__attribute__((address_space(3))) void*)(lp), 16, 0, 0)

// raw barrier (no vmcnt(0) drain) with compiler memory fences on both sides
#define BARRIER() do { asm volatile("" ::: "memory");                         \
  __builtin_amdgcn_s_barrier(); asm volatile("" ::: "memory"); } while (0)

// ---------------------------------------------------------------- hprep ----
__global__ void hprep_kernel(const float* ar, const float* ap, const float* ao,
                             const float* mr, const float* mp, const float* mo,
                             float* HS) {
  if (threadIdx.x != 0) return;
  const float* L[2] = {ar, mr};
  const float* P[2] = {ap, mp};
  const float* O[2] = {ao, mo};
  for (int s = 0; s < 2; ++s) {
    float A[16];
    for (int i = 0; i < 16; ++i) A[i] = expf(L[s][i]);
    for (int it = 0; it < 20; ++it) {
      for (int r = 0; r < 4; ++r) {
        float rs = A[4*r] + A[4*r+1] + A[4*r+2] + A[4*r+3] + 1e-8f;
        for (int c = 0; c < 4; ++c) A[4*r+c] /= rs;
      }
      for (int c = 0; c < 4; ++c) {
        float cs = A[c] + A[4+c] + A[8+c] + A[12+c] + 1e-8f;
        for (int r = 0; r < 4; ++r) A[4*r+c] /= cs;
      }
    }
    float* dst = HS + s * 24;
    for (int i = 0; i < 16; ++i) dst[i] = A[i];
    {
      float m = fmaxf(fmaxf(P[s][0], P[s][1]), fmaxf(P[s][2], P[s][3]));
      float e[4], t = 0.f;
      for (int i = 0; i < 4; ++i) { e[i] = expf(P[s][i] - m); t += e[i]; }
      for (int i = 0; i < 4; ++i) dst[16 + i] = e[i] / t;
    }
    {
      float m = fmaxf(fmaxf(O[s][0], O[s][1]), fmaxf(O[s][2], O[s][3]));
      float e[4], t = 0.f;
      for (int i = 0; i < 4; ++i) { e[i] = expf(O[s][i] - m); t += e[i]; }
      for (int i = 0; i < 4; ++i) dst[20 + i] = e[i] / t;
    }
  }
}

// ------------------------------------------------------------------ cvt ----
__global__ void cvt_kernel(const float* __restrict__ in, bf16* __restrict__ out, int n4) {
  int i = blockIdx.x * 256 + threadIdx.x;
  const int st = gridDim.x * 256;
  for (; i < n4; i += st) {
    const float4 v = ((const float4*)in)[i];
    bf16x4 o = {(bf16)v.x, (bf16)v.y, (bf16)v.z, (bf16)v.w};
    *(bf16x4*)(out + (size_t)i * 4) = o;
  }
}

// ---------------------------------------------------------------- preln ----
__global__ __launch_bounds__(256) void preln_kernel(
    const float* __restrict__ x, const float* __restrict__ H,
    const float* __restrict__ g, const float* __restrict__ b,
    bf16* __restrict__ out) {
  const int t = blockIdx.x;
  const float* xr = x + (size_t)t * EMBED;
  __shared__ float s[CHUNK];
  __shared__ float part[8];
  __shared__ float red[2];
  const int tid = threadIdx.x;
  float sv = 0.f;
  if (tid < CHUNK) {
    sv = H[0]*xr[tid] + H[1]*xr[CHUNK+tid] + H[2]*xr[2*CHUNK+tid] + H[3]*xr[3*CHUNK+tid];
    s[tid] = sv;
  }
  float sum = sv, sq = sv * sv;
  #pragma unroll
  for (int m = 32; m > 0; m >>= 1) {
    sum += __shfl_down(sum, m);
    sq  += __shfl_down(sq, m);
  }
  if ((tid & 63) == 0) { part[tid >> 6] = sum; part[4 + (tid >> 6)] = sq; }
  __syncthreads();
  if (tid == 0) {
    float S = part[0] + part[1] + part[2] + part[3];
    float Q = part[4] + part[5] + part[6] + part[7];
    float mu = S * (1.f / CHUNK);
    float var = Q * (1.f / CHUNK) - mu * mu;
    red[0] = mu;
    red[1] = rsqrtf(var + 1e-5f);
  }
  __syncthreads();
  const float mu = red[0], rs = red[1];
  bf16* orow = out + (size_t)t * EMBED;
  #pragma unroll
  for (int r = 0; r < 3; ++r) {
    const int d = tid + r * 256;
    const float v = (s[d % CHUNK] - mu) * rs * g[d] + b[d];
    orow[d] = (bf16)v;
  }
}

// ----------------------------------------------------------------- gemm ----
// C[m,n] = sum_k A[m,k]*B[n,k] + bias[n]; bf16 row-major A (MxK), B (NxK).
// 128x128 tile, BK=32, double-buffered LDS, counted vmcnt, raw barriers (T3).
// T1 XCD block swizzle (grids all have nwg % 8 == 0).
template <int GELU, int OUTF32>
__global__ __launch_bounds__(256) void gemm_bt(
    const bf16* __restrict__ A, const bf16* __restrict__ B,
    const float* __restrict__ bias, void* __restrict__ Cout,
    int M, int N, int K) {
  constexpr int BM = 128, BN = 128, BK = 32;
  __shared__ bf16 sA[2][BM * BK];
  __shared__ bf16 sB[2][BN * BK];
  const int tid  = threadIdx.x;
  const int lane = tid & 63;
  const int nwg = gridDim.x * gridDim.y;
  int Lw = blockIdx.y * gridDim.x + blockIdx.x;
  Lw = (Lw & 7) * (nwg >> 3) + (Lw >> 3);
  const int bm = (Lw / gridDim.x) * BM;
  const int bn = (Lw % gridDim.x) * BN;
  const int wave = tid >> 6;
  const int wr = (wave >> 1) * 64;
  const int wc = (wave & 1) * 64;
  f32x4 acc[4][4] = {};
  const int tr = tid >> 2;          // 0..63  staging row
  const int tc = (tid & 3) * 8;     // 0,8,16,24
  const bf16* Ag = A + (size_t)(bm + tr) * K + tc;
  const bf16* Bg = B + (size_t)(bn + tr) * K + tc;
  const int lofs = tr * BK + tc;
  const int arow = wr + (lane & 15);
  const int brow = wc + (lane & 15);
  const int k0 = (lane >> 4) * 8;
  const int nst = K / BK;
  // prologue: stage tile 0 into buf 0
  GLDS16(Ag, sA[0] + lofs);
  GLDS16(Ag + (size_t)64 * K, sA[0] + lofs + 64 * BK);
  GLDS16(Bg, sB[0] + lofs);
  GLDS16(Bg + (size_t)64 * K, sB[0] + lofs + 64 * BK);
  for (int t = 0; t < nst; ++t) {
    const int cur = t & 1;
    if (t + 1 < nst) {
      const int bk = (t + 1) * BK;
      GLDS16(Ag + bk, sA[cur ^ 1] + lofs);
      GLDS16(Ag + (size_t)64 * K + bk, sA[cur ^ 1] + lofs + 64 * BK);
      GLDS16(Bg + bk, sB[cur ^ 1] + lofs);
      GLDS16(Bg + (size_t)64 * K + bk, sB[cur ^ 1] + lofs + 64 * BK);
      asm volatile("s_waitcnt vmcnt(4)" ::: "memory");
    } else {
      asm volatile("s_waitcnt vmcnt(0)" ::: "memory");
    }
    BARRIER();
    bf16x8 af[4], bfr[4];
    #pragma unroll
    for (int i = 0; i < 4; ++i) af[i] = *(const bf16x8*)(sA[cur] + (arow + i * 16) * BK + k0);
    #pragma unroll
    for (int j = 0; j < 4; ++j) bfr[j] = *(const bf16x8*)(sB[cur] + (brow + j * 16) * BK + k0);
    #pragma unroll
    for (int i = 0; i < 4; ++i)
      #pragma unroll
      for (int j = 0; j < 4; ++j)
        acc[i][j] = __builtin_amdgcn_mfma_f32_16x16x32_bf16(af[i], bfr[j], acc[i][j], 0, 0, 0);
    BARRIER();
  }
  const int row0 = bm + wr + ((lane >> 4) * 4);
  const int col0 = bn + wc + (lane & 15);
  #pragma unroll
  for (int j = 0; j < 4; ++j) {
    const int col = col0 + j * 16;
    const float bv = bias[col];
    #pragma unroll
    for (int i = 0; i < 4; ++i) {
      #pragma unroll
      for (int r = 0; r < 4; ++r) {
        float v = acc[i][j][r] + bv;
        if (GELU) v = 0.5f * v * (1.f + erff(v * 0.70710678118654752f));
        const size_t off = (size_t)(row0 + i * 16 + r) * N + col;
        if (OUTF32) ((float*)Cout)[off] = v;
        else        ((bf16*)Cout)[off] = (bf16)v;
      }
    }
  }
}

// ------------------------------------------------------------------- vt ----
// VT[bh][hd][tok] = qkv[bb*1024+tok][1536 + h*64 + hd]; swizzled LDS stage.
__global__ __launch_bounds__(256) void vt_kernel(const bf16* __restrict__ qkv,
                                                 bf16* __restrict__ VT) {
  const int tt = blockIdx.x;   // 16 tok tiles of 64
  const int bh = blockIdx.y;   // 96
  const int bb = bh / HEADS;
  const int h = bh - bb * HEADS;
  __shared__ bf16 sT[64 * 64];
  const int t = threadIdx.x;
  const int srow = t >> 3;            // 0..31 (tok within half-tile)
  const int g = t & 7;                // 16B granule
  const int gs = ((g ^ (srow & 7)) * 8);
  const bf16* Vg = qkv + ((size_t)(bb * SEQ + tt * 64 + srow)) * 2304 + 1536 + h * 64;
  GLDS16(Vg + gs, sT + srow * 64 + g * 8);
  GLDS16(Vg + (size_t)32 * 2304 + gs, sT + (32 + srow) * 64 + g * 8);
  __syncthreads();
  const int hd = t >> 2;
  const int tg = (t & 3) * 16;
  bf16 tmp[16];
  #pragma unroll
  for (int j = 0; j < 16; ++j) {
    const int tok = tg + j;
    tmp[j] = sT[tok * 64 + (hd ^ ((tok & 7) << 3))];
  }
  bf16* op = VT + (size_t)bh * (HD * SEQ) + (size_t)hd * SEQ + tt * 64 + tg;
  *(bf16x8*)(op) = *(const bf16x8*)(tmp);
  *(bf16x8*)(op + 8) = *(const bf16x8*)(tmp + 8);
}

// ----------------------------------------------------------------- attn ----
// Flash attention, swizzled LDS, double-buffered K/V staging (T3),
// row-sum computed via extra ones-column MFMA group (nj=4) instead of a
// shuffle tree — o[4] obeys the same alpha recurrence as the softmax l.
__global__ __launch_bounds__(256) void attn_kernel(
    const bf16* __restrict__ qkv, const bf16* __restrict__ VT,
    bf16* __restrict__ out) {
  const int qt = blockIdx.x;
  const int bh = blockIdx.y;
  const int bb = bh / HEADS;
  const int h = bh - bb * HEADS;
  const int tid = threadIdx.x;
  const int lane = tid & 63;
  const int wave = tid >> 6;
  const size_t tokBase = (size_t)bb * SEQ;
  const int q0 = qt * 64;

  __shared__ bf16 sQ[64 * 64];
  __shared__ bf16 sK[2][64 * 64];
  __shared__ bf16 sV[2][80 * 64];   // rows 0..63 V^T tile; row 64 = ones, 65..79 = 0
  __shared__ bf16 sP[4][16 * 64];   // per wave, swizzled

  // init ones/zero rows of both V buffers (persist across staging)
  for (int idx = tid; idx < 16 * 64; idx += 256) {
    const bf16 v = (idx < 64) ? (bf16)1.f : (bf16)0.f;
    sV[0][64 * 64 + idx] = v;
    sV[1][64 * 64 + idx] = v;
  }

  const int srow = tid >> 3;          // 0..31
  const int g = tid & 7;
  const int gs = ((g ^ (srow & 7)) * 8);   // pre-swizzled source granule
  {
    const bf16* Qg = qkv + (tokBase + q0 + srow) * 2304 + h * 64;
    GLDS16(Qg + gs, sQ + srow * 64 + g * 8);
    GLDS16(Qg + (size_t)32 * 2304 + gs, sQ + (32 + srow) * 64 + g * 8);
  }
  __syncthreads();   // drains Q loads, publishes ones rows
  const int l15 = lane & 15, hi = lane >> 4;
  const int ksw = (l15 & 7) << 3;
  bf16x8 qf[2];
  {
    const int qrow = wave * 16 + l15;
    const int qsw = (qrow & 7) << 3;
    #pragma unroll
    for (int ks = 0; ks < 2; ++ks)
      qf[ks] = *(const bf16x8*)(sQ + qrow * 64 + ((hi * 8 + ks * 32) ^ qsw));
  }

  f32x4 o[5] = {};
  float mrun[4];
  #pragma unroll
  for (int r = 0; r < 4; ++r) mrun[r] = -1e30f;

  const bf16* Kbase = qkv + tokBase * 2304 + 768 + h * 64;
  const bf16* Vbase = VT + (size_t)bh * (HD * SEQ);

  // prologue: stage tile 0 into buf 0
  {
    const bf16* Kg = Kbase + (size_t)srow * 2304;
    GLDS16(Kg + gs, sK[0] + srow * 64 + g * 8);
    GLDS16(Kg + (size_t)32 * 2304 + gs, sK[0] + (32 + srow) * 64 + g * 8);
    const bf16* Vg = Vbase + (size_t)srow * SEQ;
    GLDS16(Vg + gs, sV[0] + srow * 64 + g * 8);
    GLDS16(Vg + (size_t)32 * SEQ + gs, sV[0] + (32 + srow) * 64 + g * 8);
  }

  for (int it = 0; it < SEQ / 64; ++it) {
    const int cur = it & 1;
    if (it + 1 < SEQ / 64) {
      const int kb = (it + 1) * 64;
      const bf16* Kg = Kbase + (size_t)(kb + srow) * 2304;
      GLDS16(Kg + gs, sK[cur ^ 1] + srow * 64 + g * 8);
      GLDS16(Kg + (size_t)32 * 2304 + gs, sK[cur ^ 1] + (32 + srow) * 64 + g * 8);
      const bf16* Vg = Vbase + (size_t)srow * SEQ + kb;
      GLDS16(Vg + gs, sV[cur ^ 1] + srow * 64 + g * 8);
      GLDS16(Vg + (size_t)32 * SEQ + gs, sV[cur ^ 1] + (32 + srow) * 64 + g * 8);
      asm volatile("s_waitcnt vmcnt(4)" ::: "memory");
    } else {
      asm volatile("s_waitcnt vmcnt(0)" ::: "memory");
    }
    BARRIER();
    // S = Q K^T  (16 x 64 per wave)
    f32x4 s[4];
    #pragma unroll
    for (int nj = 0; nj < 4; ++nj) {
      s[nj] = (f32x4){0.f, 0.f, 0.f, 0.f};
      #pragma unroll
      for (int ks = 0; ks < 2; ++ks) {
        bf16x8 kf = *(const bf16x8*)(sK[cur] + (nj * 16 + l15) * 64 + ((hi * 8 + ks * 32) ^ ksw));
        s[nj] = __builtin_amdgcn_mfma_f32_16x16x32_bf16(qf[ks], kf, s[nj], 0, 0, 0);
      }
    }
    // online softmax; scale = 1/8 — max tree only (sum via ones-MFMA)
    float p[4][4], tmax[4];
    #pragma unroll
    for (int r = 0; r < 4; ++r) {
      float m = fmaxf(fmaxf(s[0][r], s[1][r]), fmaxf(s[2][r], s[3][r]));
      tmax[r] = m * 0.125f;
    }
    #pragma unroll
    for (int r = 0; r < 4; ++r) {
      #pragma unroll
      for (int mm = 1; mm < 16; mm <<= 1) tmax[r] = fmaxf(tmax[r], __shfl_xor(tmax[r], mm));
    }
    float alpha[4];
    #pragma unroll
    for (int r = 0; r < 4; ++r) {
      const float mnew = fmaxf(mrun[r], tmax[r]);
      alpha[r] = __expf(mrun[r] - mnew);
      mrun[r] = mnew;
      #pragma unroll
      for (int nj = 0; nj < 4; ++nj)
        p[nj][r] = __expf(s[nj][r] * 0.125f - mnew);
    }
    #pragma unroll
    for (int nj = 0; nj < 5; ++nj)
      #pragma unroll
      for (int r = 0; r < 4; ++r)
        o[nj][r] *= alpha[r];
    // P -> LDS (per-wave, swizzled; intra-wave DS ordering gives visibility)
    bf16* Pw = sP[wave];
    #pragma unroll
    for (int r = 0; r < 4; ++r) {
      const int prow = hi * 4 + r;
      const int psw = (prow & 7) << 3;
      #pragma unroll
      for (int nj = 0; nj < 4; ++nj)
        Pw[prow * 64 + ((nj * 16 + l15) ^ psw)] = (bf16)p[nj][r];
    }
    // O += P V  (nj = 4 accumulates the row-sum l via the ones row)
    #pragma unroll
    for (int ks = 0; ks < 2; ++ks) {
      bf16x8 pa = *(const bf16x8*)(Pw + l15 * 64 + ((hi * 8 + ks * 32) ^ ksw));
      #pragma unroll
      for (int nj = 0; nj < 5; ++nj) {
        bf16x8 vb = *(const bf16x8*)(sV[cur] + (nj * 16 + l15) * 64 + ((hi * 8 + ks * 32) ^ ksw));
        o[nj] = __builtin_amdgcn_mfma_f32_16x16x32_bf16(pa, vb, o[nj], 0, 0, 0);
      }
    }
    BARRIER();
  }
  #pragma unroll
  for (int r = 0; r < 4; ++r) {
    const float lsum = __shfl(o[4][r], hi << 4, 64);   // lane (hi,l15=0) holds l
    const float inv = 1.f / lsum;
    const size_t row = tokBase + q0 + wave * 16 + hi * 4 + r;
    bf16* orow = out + row * EMBED + h * 64;
    #pragma unroll
    for (int nj = 0; nj < 4; ++nj)
      orow[nj * 16 + l15] = (bf16)(o[nj][r] * inv);
  }
}

// -------------------------------------------------------------- combine ----
__global__ void combine_kernel(const float* __restrict__ xs, const float* __restrict__ t,
                               const float* __restrict__ Hres, const float* __restrict__ Hpost,
                               float* __restrict__ outp) {
  const int idx = blockIdx.x * 256 + threadIdx.x;
  if (idx >= TOKENS * CHUNK) return;
  const int tok = idx / CHUNK;
  const int c = idx - tok * CHUNK;
  const float* xr = xs + (size_t)tok * EMBED + c;
  const float* tr = t + (size_t)tok * EMBED + c;
  const float x0 = xr[0], x1 = xr[CHUNK], x2 = xr[2 * CHUNK], x3 = xr[3 * CHUNK];
  const float tm = 0.25f * (tr[0] + tr[CHUNK] + tr[2 * CHUNK] + tr[3 * CHUNK]);
  #pragma unroll
  for (int n = 0; n < 4; ++n) {
    const float v = Hres[4*n+0]*x0 + Hres[4*n+1]*x1 + Hres[4*n+2]*x2 + Hres[4*n+3]*x3
                  + Hpost[n] * tm;
    outp[(size_t)tok * EMBED + n * CHUNK + c] = v;
  }
}

// ---------------------------------------------------------------- launch ---
extern "C" void kernel_launch(void* const* d_in, const int* in_sizes, int n_in,
                              void* d_out, int out_size, void* d_ws, size_t ws_size,
                              hipStream_t stream) {
  const float* x       = (const float*)d_in[0];
  const float* ln1_g   = (const float*)d_in[1];
  const float* ln1_b   = (const float*)d_in[2];
  const float* ln2_g   = (const float*)d_in[3];
  const float* ln2_b   = (const float*)d_in[4];
  const float* qkv_w   = (const float*)d_in[5];
  const float* qkv_b   = (const float*)d_in[6];
  const float* proj_w  = (const float*)d_in[7];
  const float* proj_b  = (const float*)d_in[8];
  const float* fc1_w   = (const float*)d_in[9];
  const float* fc1_b   = (const float*)d_in[10];
  const float* fc2_w   = (const float*)d_in[11];
  const float* fc2_b   = (const float*)d_in[12];
  const float* a_hres  = (const float*)d_in[13];
  const float* a_hpre  = (const float*)d_in[14];
  const float* a_hpost = (const float*)d_in[15];
  const float* m_hres  = (const float*)d_in[16];
  const float* m_hpre  = (const float*)d_in[17];
  const float* m_hpost = (const float*)d_in[18];

  char* ws = (char*)d_ws;
  float* HS = (float*)(ws);                                  // 48 floats
  bf16* Wq  = (bf16*)(ws + 1024);                            // 2304x768
  bf16* Wp  = (bf16*)(ws + 1024 + 3538944);                  // 768x768
  bf16* W1  = (bf16*)(ws + 1024 + 3538944 + 1179648);        // 3072x768
  bf16* W2  = (bf16*)(ws + 1024 + 3538944 + 1179648 + 4718592); // 768x3072
  bf16* LN  = (bf16*)(ws + 14156800);                        // 8192x768 bf16
  float* T  = (float*)(ws + 26739712);                       // 8192x768 f32
  float* X2 = (float*)(ws + 51905536);                       // 8192x768 f32
  bf16* QKV = (bf16*)(ws + 77071360);                        // 8192x2304 bf16
  bf16* AO  = (bf16*)(ws + 114820096);                       // 8192x768 bf16
  bf16* Hm  = (bf16*)(ws + 77071360);                        // 8192x3072 (overlays QKV+AO)
  bf16* VT  = LN;   // 96x64x1024 bf16 — overlays LN (dead after qkv GEMM)

  hprep_kernel<<<1, 64, 0, stream>>>(a_hres, a_hpre, a_hpost, m_hres, m_hpre, m_hpost, HS);
  cvt_kernel<<<1024, 256, 0, stream>>>(qkv_w, Wq, 2304 * 768 / 4);
  cvt_kernel<<<1024, 256, 0, stream>>>(proj_w, Wp, 768 * 768 / 4);
  cvt_kernel<<<1024, 256, 0, stream>>>(fc1_w, W1, 3072 * 768 / 4);
  cvt_kernel<<<1024, 256, 0, stream>>>(fc2_w, W2, 768 * 3072 / 4);

  // ---- block 1: attention mhc ----
  preln_kernel<<<TOKENS, 256, 0, stream>>>(x, HS + 16, ln1_g, ln1_b, LN);
  gemm_bt<0, 0><<<dim3(2304 / 128, TOKENS / 128), 256, 0, stream>>>(LN, Wq, qkv_b, QKV, TOKENS, 2304, 768);
  vt_kernel<<<dim3(16, 96), 256, 0, stream>>>(QKV, VT);
  attn_kernel<<<dim3(16, 96), 256, 0, stream>>>(QKV, VT, AO);
  gemm_bt<0, 1><<<dim3(768 / 128, TOKENS / 128), 256, 0, stream>>>(AO, Wp, proj_b, T, TOKENS, 768, 768);
  combine_kernel<<<(TOKENS * CHUNK + 255) / 256, 256, 0, stream>>>(x, T, HS + 0, HS + 20, X2);

  // ---- block 2: MLP mhc ----
  preln_kernel<<<TOKENS, 256, 0, stream>>>(X2, HS + 24 + 16, ln2_g, ln2_b, LN);
  gemm_bt<1, 0><<<dim3(3072 / 128, TOKENS / 128), 256, 0, stream>>>(LN, W1, fc1_b, Hm, TOKENS, 3072, 768);
  gemm_bt<0, 1><<<dim3(768 / 128, TOKENS / 128), 256, 0, stream>>>(Hm, W2, fc2_b, T, TOKENS, 768, 3072);
  combine_kernel<<<(TOKENS * CHUNK + 255) / 256, 256, 0, stream>>>(X2, T, HS + 24, HS + 24 + 20, (float*)d_out);
}